// Round 4
// baseline (275.218 us; speedup 1.0000x reference)
//
#include <hip/hip_runtime.h>
#include <math.h>

#define BATCH 32
#define HIN   224
#define WIN   224
#define CIN   3
#define KOUT  64
#define RK    5
#define HOUT  220
#define WOUT  220

#define TS     16                 // output tile: 16x16 pixels
#define PATCH  20
#define SROWS  24                 // staged rows (20 + 4 overfetch for kh up to 5; clamped)
#define NTOT ((size_t)BATCH * HOUT * WOUT * KOUT)

typedef float  v4f    __attribute__((ext_vector_type(4)));
typedef short  short8 __attribute__((ext_vector_type(8)));   // 8 bf16 = 4 VGPRs

// d_ws layout: [0,12288): 768 x short8 weight frags  [12288,12544): 64 f32 softplus(w_sigma)
#define WS_WF_FRAGS 768
#define WS_WSG_OFF  12288

// --- HW transcendentals: v_exp_f32 = 2^x, v_log_f32 = log2(x) ---
__device__ __forceinline__ float exp2_hw(float x) { float r; asm("v_exp_f32 %0, %1" : "=v"(r) : "v"(x)); return r; }
__device__ __forceinline__ float log2_hw(float x) { float r; asm("v_log_f32 %0, %1" : "=v"(r) : "v"(x)); return r; }
#define LOG2E 1.44269504088896f
#define LN2   0.69314718055995f

__device__ __forceinline__ float softplus_hw(float x) {       // general, stable
    float t = exp2_hw(-fabsf(x) * LOG2E);
    return fmaxf(x, 0.0f) + LN2 * log2_hw(1.0f + t);
}
__device__ __forceinline__ float softplus_pos(float y) {      // y >= 0 fast path
    return y + LN2 * log2_hw(1.0f + exp2_hw(-y * LOG2E));
}
__device__ __forceinline__ short f2bf(float x) {              // f32 -> bf16 bits, RNE
    unsigned u = __float_as_uint(x);
    u = (u + 0x7FFFu + ((u >> 16) & 1u)) >> 16;
    return (short)u;
}

// ---- prep: pack weight MFMA fragments (bf16) + softplus(w_sigma) into d_ws ----
// A-frag layout (16x16x32, M=16 ch): row = lane&15 (ch low), k = (lane>>4)*8 + i.
// k-order: k = kh*16 + (kw*3 + c); inner==15 and k>=80 are zero pads.
__global__ __launch_bounds__(256) void vdp_prep_kernel(
    const float* __restrict__ w_mu, const float* __restrict__ w_sigma, void* __restrict__ ws)
{
    short8* wf = (short8*)ws;
    float* wsg = (float*)((char*)ws + WS_WSG_OFF);
    const int t = threadIdx.x;
    for (int f = t; f < WS_WF_FRAGS; f += 256) {   // f = (s*4+nb)*64 + lane
        const int s  = f >> 8;
        const int nb = (f >> 6) & 3;
        const int l  = f & 63;
        const int ch = nb * 16 + (l & 15);
        const int h2 = l >> 4;
        short8 r;
        #pragma unroll
        for (int i = 0; i < 8; ++i) {
            const int k = s * 32 + h2 * 8 + i;
            const int kh = k >> 4, inner = k & 15;
            float v = 0.0f;
            if (inner < 15 && k < 80) {
                const int kw = inner / 3;
                const int c  = inner - kw * 3;
                v = w_mu[((kh * 5 + kw) * 3 + c) * KOUT + ch];
            }
            r[i] = f2bf(v);
        }
        wf[f] = r;
    }
    if (t < KOUT) wsg[t] = softplus_hw(w_sigma[t]);
}

__global__ __launch_bounds__(256, 2) void vdp_conv_kernel(
    const float* __restrict__ mu_in, const void* __restrict__ ws, float* __restrict__ out)
{
    __shared__ float s_row[SROWS][64];     // staged rows, elems = px*3+c (60 valid + 4 zero)
    __shared__ float s_ssq[PATCH][PATCH];  // per-pixel sum_c x^2
    __shared__ float s_sq[TS * TS];        // 5x5 box mean of s_ssq

    const int tid  = threadIdx.x;
    const int lane = tid & 63;
    const int wid  = tid >> 6;
    const int p    = lane & 15;
    const int h2   = lane >> 4;

    const int b = blockIdx.z;
    int ho0 = blockIdx.y * TS; if (ho0 > HOUT - TS) ho0 = HOUT - TS;  // overlap recompute (identical values)
    int wo0 = blockIdx.x * TS; if (wo0 > WOUT - TS) wo0 = WOUT - TS;

    // ---- weight frags + sigma scales from d_ws (L2-hot, coalesced) ----
    const short8* wfg = (const short8*)ws;
    short8 wf[12];
    #pragma unroll
    for (int f = 0; f < 12; ++f) wf[f] = wfg[f * 64 + lane];
    const float* wsg_g = (const float*)((const char*)ws + WS_WSG_OFF);
    v4f wsg[4];
    #pragma unroll
    for (int nb = 0; nb < 4; ++nb) wsg[nb] = *(const v4f*)(wsg_g + nb * 16 + h2 * 4);

    // ---- stage input rows (row-clamped; cols 60..63 zeroed) ----
    for (int idx = tid; idx < SROWS * 64; idx += 256) {
        const int r = idx >> 6, c = idx & 63;
        int rg = ho0 + r; if (rg > HIN - 1) rg = HIN - 1;
        float v = 0.0f;
        if (c < 60) v = mu_in[(((size_t)b * HIN + rg) * WIN + wo0) * CIN + c];
        s_row[r][c] = v;
    }
    __syncthreads();

    // ---- per-pixel channel-summed squares ----
    for (int idx = tid; idx < PATCH * PATCH; idx += 256) {
        const int r = idx / PATCH;
        const int px = idx - r * PATCH;
        const float x0 = s_row[r][3 * px], x1 = s_row[r][3 * px + 1], x2 = s_row[r][3 * px + 2];
        s_ssq[r][px] = fmaf(x0, x0, fmaf(x1, x1, x2 * x2));
    }
    __syncthreads();

    // ---- 5x5 box mean (one thread per tile pixel) ----
    {
        const int pr = tid >> 4, pc = tid & 15;
        float acc = 0.0f;
        #pragma unroll
        for (int kh = 0; kh < RK; ++kh)
            #pragma unroll
            for (int kw = 0; kw < RK; ++kw)
                acc += s_ssq[pr + kh][pc + kw];
        s_sq[tid] = acc * (1.0f / 75.0f);
    }
    __syncthreads();

    // ---- main: each wave computes 4 output rows x 16 px x 64 ch via MFMA ----
    #pragma unroll 1
    for (int j = 0; j < 4; ++j) {
        const int rt = (wid << 2) | j;

        // B-frags: lane holds patch[k = s*32 + h2*8 + i][px = p]
        short8 pf[3];
        #pragma unroll
        for (int s = 0; s < 3; ++s) {
            const float* rp = &s_row[rt + 2 * s + (h2 >> 1)][3 * p + 8 * (h2 & 1)];
            short8 r;
            #pragma unroll
            for (int i = 0; i < 8; ++i) r[i] = f2bf(rp[i]);
            pf[s] = r;
        }

        v4f acc[4];
        #pragma unroll
        for (int nb = 0; nb < 4; ++nb) {
            v4f a = {0.0f, 0.0f, 0.0f, 0.0f};
            #pragma unroll
            for (int s = 0; s < 3; ++s)
                a = __builtin_amdgcn_mfma_f32_16x16x32_bf16(wf[s * 4 + nb], pf[s], a, 0, 0, 0);
            acc[nb] = a;
        }

        // D: col = lane&15 = pixel, rows = 4 consecutive channels at nb*16 + h2*4
        const float sq = s_sq[(rt << 4) | p];
        const size_t base = (((size_t)b * HOUT + ho0 + rt) * WOUT + wo0 + p) * KOUT + h2 * 4;
        float* mp = out + base;
        float* sp = mp + NTOT;
        #pragma unroll
        for (int nb = 0; nb < 4; ++nb) {
            __builtin_nontemporal_store(acc[nb], (v4f*)(mp + nb * 16));
            v4f sg;
            sg.x = softplus_pos(wsg[nb].x * sq);
            sg.y = softplus_pos(wsg[nb].y * sq);
            sg.z = softplus_pos(wsg[nb].z * sq);
            sg.w = softplus_pos(wsg[nb].w * sq);
            __builtin_nontemporal_store(sg, (v4f*)(sp + nb * 16));
        }
    }
}

__global__ __launch_bounds__(256) void vdp_kl_kernel(
    const float* __restrict__ w_mu,
    const float* __restrict__ w_sigma,
    float* __restrict__ out)
{
    __shared__ float red[4];
    const int tid = threadIdx.x;

    float s = 0.0f;
    for (int i = tid; i < RK * RK * CIN * KOUT; i += 256) {
        const float v = w_mu[i];
        s = fmaf(v, v, s);
    }
    float u = s * (100.0f / 4800.0f);
    if (tid < KOUT) {
        const float ws = w_sigma[tid];
        u += (-ws + softplus_hw(ws) * 100.0f) * (1.0f / 64.0f);
    }
    #pragma unroll
    for (int off = 32; off > 0; off >>= 1)
        u += __shfl_down(u, off, 64);
    if ((tid & 63) == 0) red[tid >> 6] = u;
    __syncthreads();
    if (tid == 0) {
        const float U = red[0] + red[1] + red[2] + red[3];
        out[2 * NTOT] = 0.5f * (-4.6051701860f - 1.0f + U);
    }
}

extern "C" void kernel_launch(void* const* d_in, const int* in_sizes, int n_in,
                              void* d_out, int out_size, void* d_ws, size_t ws_size,
                              hipStream_t stream)
{
    (void)in_sizes; (void)n_in; (void)ws_size; (void)out_size;
    const float* mu_in   = (const float*)d_in[0];
    const float* w_mu    = (const float*)d_in[1];
    const float* w_sigma = (const float*)d_in[2];
    float* out = (float*)d_out;

    vdp_prep_kernel<<<1, 256, 0, stream>>>(w_mu, w_sigma, d_ws);
    dim3 grid((WOUT + TS - 1) / TS, (HOUT + TS - 1) / TS, BATCH);  // 14 x 14 x 32
    vdp_conv_kernel<<<grid, 256, 0, stream>>>(mu_in, d_ws, out);
    vdp_kl_kernel<<<1, 256, 0, stream>>>(w_mu, w_sigma, out);
}

// Round 5
// 191.453 us; speedup vs baseline: 1.4375x; 1.4375x over previous
//
#include <hip/hip_runtime.h>
#include <math.h>

#define BATCH 32
#define HIN   224
#define WIN   224
#define CIN   3
#define KOUT  64
#define RK    5
#define HOUT  220
#define WOUT  220

#define TS     16                 // output tile: 16x16 pixels
#define PATCH  20
#define SROWS  24                 // staged rows (row-clamped overfetch)
#define NTOT ((size_t)BATCH * HOUT * WOUT * KOUT)

typedef float  v4f    __attribute__((ext_vector_type(4)));
typedef short  short8 __attribute__((ext_vector_type(8)));   // 8 bf16 = 4 VGPRs

// d_ws layout: [0,12288): 768 x short8 weight frags  [12288,12544): 64 f32 softplus(w_sigma)
#define WS_WF_FRAGS 768
#define WS_WSG_OFF  12288

// --- HW transcendentals: v_exp_f32 = 2^x, v_log_f32 = log2(x) ---
__device__ __forceinline__ float exp2_hw(float x) { float r; asm("v_exp_f32 %0, %1" : "=v"(r) : "v"(x)); return r; }
__device__ __forceinline__ float log2_hw(float x) { float r; asm("v_log_f32 %0, %1" : "=v"(r) : "v"(x)); return r; }
#define LOG2E 1.44269504088896f
#define LN2   0.69314718055995f

__device__ __forceinline__ float softplus_hw(float x) {       // general, stable
    float t = exp2_hw(-fabsf(x) * LOG2E);
    return fmaxf(x, 0.0f) + LN2 * log2_hw(1.0f + t);
}
__device__ __forceinline__ float softplus_pos(float y) {      // y >= 0 fast path
    return y + LN2 * log2_hw(1.0f + exp2_hw(-y * LOG2E));
}
__device__ __forceinline__ short f2bf(float x) {              // f32 -> bf16 bits, RNE
    unsigned u = __float_as_uint(x);
    u = (u + 0x7FFFu + ((u >> 16) & 1u)) >> 16;
    return (short)u;
}

// ---- prep: pack weight MFMA fragments (bf16) + softplus(w_sigma) into d_ws ----
// A-frag (16x16x32, M=16 ch): row = lane&15, k = (lane>>4)*8 + i.
// k-order: k = kh*16 + (kw*3 + c); inner==15 and k>=80 are zero pads.
__global__ __launch_bounds__(256) void vdp_prep_kernel(
    const float* __restrict__ w_mu, const float* __restrict__ w_sigma, void* __restrict__ ws)
{
    short8* wf = (short8*)ws;
    float* wsg = (float*)((char*)ws + WS_WSG_OFF);
    const int t = threadIdx.x;
    for (int f = t; f < WS_WF_FRAGS; f += 256) {   // f = (s*4+nb)*64 + lane
        const int s  = f >> 8;
        const int nb = (f >> 6) & 3;
        const int l  = f & 63;
        const int ch = nb * 16 + (l & 15);
        const int h2 = l >> 4;
        short8 r;
        #pragma unroll
        for (int i = 0; i < 8; ++i) {
            const int k = s * 32 + h2 * 8 + i;
            const int kh = k >> 4, inner = k & 15;
            float v = 0.0f;
            if (inner < 15 && k < 80) {
                const int kw = inner / 3;
                const int c  = inner - kw * 3;
                v = w_mu[((kh * 5 + kw) * 3 + c) * KOUT + ch];
            }
            r[i] = f2bf(v);
        }
        wf[f] = r;
    }
    if (t < KOUT) wsg[t] = softplus_hw(w_sigma[t]);
}

__global__ __launch_bounds__(256, 4) void vdp_conv_kernel(
    const float* __restrict__ mu_in, const void* __restrict__ ws, float* __restrict__ out)
{
    __shared__ float s_row[SROWS][64];     // staged rows, elems = px*3+c (60 valid + 4 zero)
    __shared__ float s_ssq[PATCH][PATCH];  // per-pixel sum_c x^2
    __shared__ float s_sq[TS * TS];        // 5x5 box mean of s_ssq

    const int tid  = threadIdx.x;
    const int lane = tid & 63;
    const int wid  = tid >> 6;
    const int p    = lane & 15;            // MFMA: pixel col; sigma: ch-group kg
    const int h2   = lane >> 4;            // MFMA: k subgroup;  sigma: px quad q

    const int b = blockIdx.z;
    int ho0 = blockIdx.y * TS; if (ho0 > HOUT - TS) ho0 = HOUT - TS;  // overlap recompute (identical values)
    int wo0 = blockIdx.x * TS; if (wo0 > WOUT - TS) wo0 = WOUT - TS;

    // ---- weight frags (L2-hot, coalesced) + sigma scale for kg-layout ----
    const short8* wfg = (const short8*)ws;
    short8 wf[12];
    #pragma unroll
    for (int f = 0; f < 12; ++f) wf[f] = wfg[f * 64 + lane];
    const float* wsg_g = (const float*)((const char*)ws + WS_WSG_OFF);
    const v4f wsg_kg = *(const v4f*)(wsg_g + p * 4);   // sigma path: ch = 4*kg .. +3

    // ---- stage input rows (row-clamped; cols 60..63 zeroed) ----
    for (int idx = tid; idx < SROWS * 64; idx += 256) {
        const int r = idx >> 6, c = idx & 63;
        int rg = ho0 + r; if (rg > HIN - 1) rg = HIN - 1;
        float v = 0.0f;
        if (c < 60) v = mu_in[(((size_t)b * HIN + rg) * WIN + wo0) * CIN + c];
        s_row[r][c] = v;
    }
    __syncthreads();

    // ---- per-pixel channel-summed squares ----
    for (int idx = tid; idx < PATCH * PATCH; idx += 256) {
        const int r = idx / PATCH;
        const int px = idx - r * PATCH;
        const float x0 = s_row[r][3 * px], x1 = s_row[r][3 * px + 1], x2 = s_row[r][3 * px + 2];
        s_ssq[r][px] = fmaf(x0, x0, fmaf(x1, x1, x2 * x2));
    }
    __syncthreads();

    // ---- 5x5 box mean (one thread per tile pixel) ----
    {
        const int pr = tid >> 4, pc = tid & 15;
        float acc = 0.0f;
        #pragma unroll
        for (int kh = 0; kh < RK; ++kh)
            #pragma unroll
            for (int kw = 0; kw < RK; ++kw)
                acc += s_ssq[pr + kh][pc + kw];
        s_sq[tid] = acc * (1.0f / 75.0f);
    }
    __syncthreads();

    // ---- main: each wave computes 4 output rows x 16 px x 64 ch ----
    #pragma unroll 1
    for (int j = 0; j < 4; ++j) {
        const int rt = (wid << 2) | j;
        const size_t rowbase = (((size_t)b * HOUT + ho0 + rt) * WOUT + wo0) * KOUT;

        // B-frags: lane holds patch[k = s*32 + h2*8 + i][px = p]
        short8 pf[3];
        #pragma unroll
        for (int s = 0; s < 3; ++s) {
            const float* rp = &s_row[rt + 2 * s + (h2 >> 1)][3 * p + 8 * (h2 & 1)];
            short8 r;
            #pragma unroll
            for (int i = 0; i < 8; ++i) r[i] = f2bf(rp[i]);
            pf[s] = r;
        }

        v4f acc[4];
        #pragma unroll
        for (int nb = 0; nb < 4; ++nb) {
            v4f a = {0.0f, 0.0f, 0.0f, 0.0f};
            #pragma unroll
            for (int s = 0; s < 3; ++s)
                a = __builtin_amdgcn_mfma_f32_16x16x32_bf16(wf[s * 4 + nb], pf[s], a, 0, 0, 0);
            acc[nb] = a;
        }

        // mu: D col = pixel p, rows = 4 ch at nb*16 + h2*4 (plain stores -> L2 combines)
        float* mp = out + rowbase + (size_t)p * KOUT + h2 * 4;
        #pragma unroll
        for (int nb = 0; nb < 4; ++nb)
            *(v4f*)(mp + nb * 16) = acc[nb];

        // sigma: MFMA-independent; kg-layout -> 4x256B contiguous wave-stores
        float* sp = out + NTOT + rowbase + p * 4;   // p = kg here
        #pragma unroll
        for (int pp = 0; pp < 4; ++pp) {
            const int px = (h2 << 2) | pp;          // h2 = px quad
            const float sq = s_sq[(rt << 4) | px];
            v4f sg;
            sg.x = softplus_pos(wsg_kg.x * sq);
            sg.y = softplus_pos(wsg_kg.y * sq);
            sg.z = softplus_pos(wsg_kg.z * sq);
            sg.w = softplus_pos(wsg_kg.w * sq);
            *(v4f*)(sp + (size_t)px * KOUT) = sg;
        }
    }
}

__global__ __launch_bounds__(256) void vdp_kl_kernel(
    const float* __restrict__ w_mu,
    const float* __restrict__ w_sigma,
    float* __restrict__ out)
{
    __shared__ float red[4];
    const int tid = threadIdx.x;

    float s = 0.0f;
    for (int i = tid; i < RK * RK * CIN * KOUT; i += 256) {
        const float v = w_mu[i];
        s = fmaf(v, v, s);
    }
    float u = s * (100.0f / 4800.0f);
    if (tid < KOUT) {
        const float ws = w_sigma[tid];
        u += (-ws + softplus_hw(ws) * 100.0f) * (1.0f / 64.0f);
    }
    #pragma unroll
    for (int off = 32; off > 0; off >>= 1)
        u += __shfl_down(u, off, 64);
    if ((tid & 63) == 0) red[tid >> 6] = u;
    __syncthreads();
    if (tid == 0) {
        const float U = red[0] + red[1] + red[2] + red[3];
        out[2 * NTOT] = 0.5f * (-4.6051701860f - 1.0f + U);
    }
}

extern "C" void kernel_launch(void* const* d_in, const int* in_sizes, int n_in,
                              void* d_out, int out_size, void* d_ws, size_t ws_size,
                              hipStream_t stream)
{
    (void)in_sizes; (void)n_in; (void)ws_size; (void)out_size;
    const float* mu_in   = (const float*)d_in[0];
    const float* w_mu    = (const float*)d_in[1];
    const float* w_sigma = (const float*)d_in[2];
    float* out = (float*)d_out;

    vdp_prep_kernel<<<1, 256, 0, stream>>>(w_mu, w_sigma, d_ws);
    dim3 grid((WOUT + TS - 1) / TS, (HOUT + TS - 1) / TS, BATCH);  // 14 x 14 x 32
    vdp_conv_kernel<<<grid, 256, 0, stream>>>(mu_in, d_ws, out);
    vdp_kl_kernel<<<1, 256, 0, stream>>>(w_mu, w_sigma, out);
}